// Round 2
// baseline (229.761 us; speedup 1.0000x reference)
//
#include <hip/hip_runtime.h>

#define NUM_C 1000
#define NUM_A 512

typedef float f32x4 __attribute__((ext_vector_type(4)));

// Workspace layout (bytes):
//   [0,      4096)   counts[1024]  (int)
//   [4096,   8192)   starts[1024]  (int)
//   [8192,  12288)   cursor[1024]  (int)
//   [12288, ...  )   rowlist[N]    (int)

__global__ void hist_kernel(const int4* __restrict__ labels4, int* __restrict__ counts, int n4) {
    int i = blockIdx.x * blockDim.x + threadIdx.x;
    int stride = gridDim.x * blockDim.x;
    for (; i < n4; i += stride) {
        int4 lab = labels4[i];
        atomicAdd(&counts[lab.x], 1);
        atomicAdd(&counts[lab.y], 1);
        atomicAdd(&counts[lab.z], 1);
        atomicAdd(&counts[lab.w], 1);
    }
}

__global__ void scan_kernel(const int* __restrict__ counts, int* __restrict__ starts,
                            int* __restrict__ cursor) {
    __shared__ int buf[1024];
    int t = threadIdx.x;
    int v = (t < NUM_C) ? counts[t] : 0;
    buf[t] = v;
    __syncthreads();
    for (int off = 1; off < 1024; off <<= 1) {
        int x = (t >= off) ? buf[t - off] : 0;
        __syncthreads();
        buf[t] += x;
        __syncthreads();
    }
    int excl = buf[t] - v;
    if (t < NUM_C) {
        starts[t] = excl;
        cursor[t] = excl;
    }
}

__global__ void scatter_kernel(const int4* __restrict__ labels4, int* __restrict__ cursor,
                               int* __restrict__ rowlist, int n4) {
    int i = blockIdx.x * blockDim.x + threadIdx.x;
    int stride = gridDim.x * blockDim.x;
    for (; i < n4; i += stride) {
        int4 lab = labels4[i];
        int base = i * 4;
        int p0 = atomicAdd(&cursor[lab.x], 1); rowlist[p0] = base + 0;
        int p1 = atomicAdd(&cursor[lab.y], 1); rowlist[p1] = base + 1;
        int p2 = atomicAdd(&cursor[lab.z], 1); rowlist[p2] = base + 2;
        int p3 = atomicAdd(&cursor[lab.w], 1); rowlist[p3] = base + 3;
    }
}

// One block per class; 256 threads = 2 rows x 128 float4-quads.
__global__ __launch_bounds__(256) void reduce_kernel(
    const f32x4* __restrict__ F4,
    const int* __restrict__ starts, const int* __restrict__ counts,
    const int* __restrict__ rowlist, f32x4* __restrict__ out) {
    int c = blockIdx.x;
    int t = threadIdx.x;
    int half = t >> 7;     // 0/1: which row of the pair
    int q = t & 127;       // float4 index within the 512-col row
    int start = starts[c];
    int cnt = counts[c];

    f32x4 acc = {0.f, 0.f, 0.f, 0.f};

    int k = half;
    // 8 rows per iteration (4 per half), 4 outstanding 16B loads per thread
    for (; k + 6 < cnt; k += 8) {
        int r0 = __builtin_amdgcn_readfirstlane(rowlist[start + k + 0]);
        int r1 = __builtin_amdgcn_readfirstlane(rowlist[start + k + 2]);
        int r2 = __builtin_amdgcn_readfirstlane(rowlist[start + k + 4]);
        int r3 = __builtin_amdgcn_readfirstlane(rowlist[start + k + 6]);
        f32x4 v0 = F4[(size_t)r0 * (NUM_A / 4) + q];
        f32x4 v1 = F4[(size_t)r1 * (NUM_A / 4) + q];
        f32x4 v2 = F4[(size_t)r2 * (NUM_A / 4) + q];
        f32x4 v3 = F4[(size_t)r3 * (NUM_A / 4) + q];
        acc += v0 + v1 + v2 + v3;
    }
    for (; k < cnt; k += 2) {
        int r = __builtin_amdgcn_readfirstlane(rowlist[start + k]);
        acc += F4[(size_t)r * (NUM_A / 4) + q];
    }

    // combine the two halves via LDS
    __shared__ f32x4 sbuf[128];
    if (half == 1) sbuf[q] = acc;
    __syncthreads();
    if (half == 0) {
        f32x4 o = sbuf[q];
        acc += o;
        float denom = (cnt > 0) ? (float)cnt : 1.0f;
        f32x4 res = acc * (1.0f / denom);
        out[(size_t)c * (NUM_A / 4) + q] = res;
    }
}

extern "C" void kernel_launch(void* const* d_in, const int* in_sizes, int n_in,
                              void* d_out, int out_size, void* d_ws, size_t ws_size,
                              hipStream_t stream) {
    const float* features = (const float*)d_in[0];
    const int* labels = (const int*)d_in[1];
    float* out = (float*)d_out;
    int n = in_sizes[1];
    int n4 = n / 4;  // N = 262144, divisible by 4

    char* ws = (char*)d_ws;
    int* counts  = (int*)(ws + 0);
    int* starts  = (int*)(ws + 4096);
    int* cursor  = (int*)(ws + 8192);
    int* rowlist = (int*)(ws + 12288);

    hipMemsetAsync(counts, 0, 4096, stream);

    int blocks = (n4 + 255) / 256;
    if (blocks > 1024) blocks = 1024;

    hist_kernel<<<blocks, 256, 0, stream>>>((const int4*)labels, counts, n4);
    scan_kernel<<<1, 1024, 0, stream>>>(counts, starts, cursor);
    scatter_kernel<<<blocks, 256, 0, stream>>>((const int4*)labels, cursor, rowlist, n4);
    reduce_kernel<<<NUM_C, 256, 0, stream>>>((const f32x4*)features, starts, counts,
                                             rowlist, (f32x4*)out);
}